// Round 5
// baseline (637.291 us; speedup 1.0000x reference)
//
#include <hip/hip_runtime.h>
#include <hip/hip_bf16.h>

#define Sq 2048
#define Dm 2048
#define HDim 3072
#define QKVDim 9216
#define NH 24
#define DH 128
#define FF 8192
#define ATT_SCALE 0.08838834764831845f

using bf16 = __hip_bfloat16;
typedef __attribute__((ext_vector_type(8))) short bf16x8;
typedef __attribute__((ext_vector_type(4))) float f32x4;
typedef unsigned int u32;
typedef __attribute__((ext_vector_type(4))) u32 u32x4;

// async global->LDS, 16B per lane; LDS dest = wave-uniform base + lane*16
__device__ __forceinline__ void gload_lds16(const void* g, void* l) {
    __builtin_amdgcn_global_load_lds(
        (const __attribute__((address_space(1))) void*)g,
        (__attribute__((address_space(3))) void*)l, 16, 0, 0);
}

#define BARRIER() do { asm volatile("" ::: "memory"); \
    __builtin_amdgcn_s_barrier(); \
    asm volatile("" ::: "memory"); } while (0)

// ---------------- LayerNorm + RMSNorm fused ----------------
__global__ __launch_bounds__(256) void ln_rms_kernel(
    const float* __restrict__ x, const float* __restrict__ g, const float* __restrict__ b,
    const float* __restrict__ ag, float* __restrict__ xnf, bf16* __restrict__ h)
{
    __shared__ float redA[4], redB[4], redC[4];
    int row = blockIdx.x;
    int t = threadIdx.x;
    int lane = t & 63, wid = t >> 6;
    const float* xr = x + (size_t)row * Dm;

    float v[8];
    float sum = 0.f, ssq = 0.f;
#pragma unroll
    for (int i = 0; i < 8; i++) {
        float f = xr[t + 256 * i];
        v[i] = f; sum += f; ssq += f * f;
    }
#pragma unroll
    for (int off = 32; off > 0; off >>= 1) {
        sum += __shfl_down(sum, off);
        ssq += __shfl_down(ssq, off);
    }
    if (lane == 0) { redA[wid] = sum; redB[wid] = ssq; }
    __syncthreads();
    sum = redA[0] + redA[1] + redA[2] + redA[3];
    ssq = redB[0] + redB[1] + redB[2] + redB[3];
    float mu = sum * (1.f / Dm);
    float var = ssq * (1.f / Dm) - mu * mu;
    float rstd = rsqrtf(var + 1e-5f);

    float xn[8];
    float s2 = 0.f;
#pragma unroll
    for (int i = 0; i < 8; i++) {
        int col = t + 256 * i;
        float xv = (v[i] - mu) * rstd * g[col] + b[col];
        xn[i] = xv;
        xnf[(size_t)row * Dm + col] = xv;
        s2 += xv * xv;
    }
#pragma unroll
    for (int off = 32; off > 0; off >>= 1) s2 += __shfl_down(s2, off);
    if (lane == 0) redC[wid] = s2;
    __syncthreads();
    s2 = redC[0] + redC[1] + redC[2] + redC[3];
    float rms = rsqrtf(s2 * (1.f / Dm) + 1e-5f);
#pragma unroll
    for (int i = 0; i < 8; i++) {
        int col = t + 256 * i;
        h[(size_t)row * Dm + col] = __float2bfloat16(xn[i] * rms * ag[col]);
    }
}

// ---------------- transpose + fp32->bf16 convert: W[K][N] -> Wt[N][K] ----------------
__global__ __launch_bounds__(256) void transpose_cvt_kernel(
    const float* __restrict__ W, bf16* __restrict__ Wt, int K, int N)
{
    __shared__ float tile[32][33];
    int n0 = blockIdx.x * 32, k0 = blockIdx.y * 32;
    int tx = threadIdx.x & 31, ty = threadIdx.x >> 5;  // 32 x 8
#pragma unroll
    for (int j = 0; j < 32; j += 8)
        tile[ty + j][tx] = W[(size_t)(k0 + ty + j) * N + n0 + tx];
    __syncthreads();
#pragma unroll
    for (int j = 0; j < 32; j += 8)
        Wt[(size_t)(n0 + ty + j) * K + k0 + tx] = __float2bfloat16(tile[tx][ty + j]);
}

// ---------------- fp32 -> bf16 convert ----------------
__global__ __launch_bounds__(256) void cvt_bf16_kernel(
    const float* __restrict__ in, bf16* __restrict__ o, int n)
{
    int i = (blockIdx.x * 256 + threadIdx.x) * 8;
    if (i >= n) return;
    f32x4 a = *reinterpret_cast<const f32x4*>(in + i);
    f32x4 b = *reinterpret_cast<const f32x4*>(in + i + 4);
    bf16 r[8];
#pragma unroll
    for (int j = 0; j < 4; j++) { r[j] = __float2bfloat16(a[j]); r[4 + j] = __float2bfloat16(b[j]); }
    *reinterpret_cast<u32x4*>(o + i) = *reinterpret_cast<u32x4*>(r);
}

// ---------------- prefill: out[row][col] = resid[row][col] + bias[col] ----------------
__global__ __launch_bounds__(256) void prefill_kernel(
    const float* __restrict__ resid, const float* __restrict__ bias,
    float* __restrict__ o, int N)
{
    int i = (blockIdx.x * 256 + threadIdx.x) * 4;
    int col = i % N;
    f32x4 r = *reinterpret_cast<const f32x4*>(resid + i);
    f32x4 b = *reinterpret_cast<const f32x4*>(bias + col);
    f32x4 ov = {r[0] + b[0], r[1] + b[1], r[2] + b[2], r[3] + b[3]};
    *reinterpret_cast<f32x4*>(o + i) = ov;
}

// ---------------- 256x256 bf16 MFMA GEMM, 4-phase/K-tile counted-vmcnt pipeline ----
// C[M][N] = A[M][K] * Bt[N][K]^T. 512 threads = 8 waves (2M x 4N), per-wave 128x64.
// LDS: per operand 4 half-K slots [256 rows][32 K] (slot = K-half-index & 3), 128 KiB.
// Per K-tile t (K-halves 2t,2t+1): 4 phases, each {ds_read frags; stage one
// half-slot (2 x gload_lds); barrier; 16 MFMA; barrier}. Stage order: P0:A(2t+3)
// P1:B(2t+3) P2:A(2t+4) P3:B(2t+4). One counted gate per tile: vmcnt(4) at P3
// pre-barrier (per-wave vmcnt + shared barrier => all waves' halves 2t+2,2t+3
// retired before tile t+1 reads; 4 loads stay in flight). Slot reuse ledger:
// slot h&3 free from last read (barrier-delimited) until first read of h+4,
// staged >=4 phases earlier, never concurrently read+written.
// Swizzle (both sides): stored blk = logical blk ^ (row&3) within each slot;
// staging pre-swizzles the global source column, reads XOR the block index.
// EPI 0: Cb = bf16(acc)
// EPI 2: o = acc + bias; Cb = bf16(gelu_tanh(o))
// EPI 4: atomicAdd(Cf[idx], acc)            (split-K partial)
template <int EPI>
__global__ __launch_bounds__(512, 2) void gemm256_kernel(
    const bf16* __restrict__ A, const bf16* __restrict__ Bt,
    int M, int N, int K, int Ksplit,
    bf16* Cb, float* Cf, const float* __restrict__ bias)
{
    __shared__ __align__(16) bf16 As[4][256 * 32];
    __shared__ __align__(16) bf16 Bs[4][256 * 32];

    // bijective XCD swizzle (m204) over the x,y grid
    int nwg = gridDim.x * gridDim.y;
    int orig = blockIdx.y * gridDim.x + blockIdx.x;
    int qq = nwg >> 3, rr = nwg & 7;
    int xcd = orig & 7, base = orig >> 3;
    int wg = (xcd < rr ? xcd * (qq + 1) : rr * (qq + 1) + (xcd - rr) * qq) + base;
    int bx = wg % gridDim.x, by = wg / gridDim.x;

    int m0 = by * 256, n0 = bx * 256;
    int kbeg = blockIdx.z * Ksplit;
    int nt = Ksplit >> 6;                  // K-tiles of 64
    int tid = threadIdx.x;
    int lane = tid & 63, w = tid >> 6;
    int wr = w >> 2, wc = w & 3;           // 2 x 4 wave grid
    int l15 = lane & 15, lhi = lane >> 4;

    // staging geometry: wave w lane L, chunk j -> row j*128 + w*16 + (L>>2),
    // dest blk = L&3; pre-swizzled source k-block = (L&3) ^ (row&3)
    int strow = w * 16 + (lane >> 2);
    int scol = (((lane & 3) ^ ((lane >> 2) & 3)) << 3);
    const bf16* Ab = A + (size_t)(m0 + strow) * K + kbeg + scol;
    const bf16* Bb = Bt + (size_t)(n0 + strow) * K + kbeg + scol;
    int ldsoff = w * 1024;

    auto stA = [&](int h) {
        int hs = h < 2 * nt ? h : 0;       // clamp source, keep vmcnt count exact
        char* dst = (char*)&As[h & 3][0] + ldsoff;
        const bf16* s = Ab + hs * 32;
        gload_lds16(s, dst);
        gload_lds16(s + (size_t)128 * K, dst + 8192);
    };
    auto stB = [&](int h) {
        int hs = h < 2 * nt ? h : 0;
        char* dst = (char*)&Bs[h & 3][0] + ldsoff;
        const bf16* s = Bb + hs * 32;
        gload_lds16(s, dst);
        gload_lds16(s + (size_t)128 * K, dst + 8192);
    };
    auto ldA = [&](int slot, int mm) {
        int r = wr * 128 + mm * 16 + l15;
        return *reinterpret_cast<const bf16x8*>(&As[slot][r * 32 + ((lhi ^ (r & 3)) << 3)]);
    };
    auto ldB = [&](int slot, int nn) {
        int r = wc * 64 + nn * 16 + l15;
        return *reinterpret_cast<const bf16x8*>(&Bs[slot][r * 32 + ((lhi ^ (r & 3)) << 3)]);
    };

    f32x4 acc[8][4];
    const f32x4 zero4 = {0.f, 0.f, 0.f, 0.f};
#pragma unroll
    for (int mm = 0; mm < 8; mm++)
#pragma unroll
        for (int nn = 0; nn < 4; nn++) acc[mm][nn] = zero4;

    // prologue: stage halves 0,1,2 (A+B); gate on halves 0,1 (leave A2,B2 in flight)
    stA(0); stB(0); stA(1); stB(1); stA(2); stB(2);
    asm volatile("s_waitcnt vmcnt(4)" ::: "memory");
    BARRIER();

    for (int t = 0; t < nt; ++t) {
        int s0 = (2 * t) & 3, s1 = s0 + 1;
        bf16x8 a[4], b[4], a2[4];

        // ---- P0: ks=0, m 0-3 ----
#pragma unroll
        for (int mm = 0; mm < 4; mm++) a[mm] = ldA(s0, mm);
#pragma unroll
        for (int nn = 0; nn < 4; nn++) b[nn] = ldB(s0, nn);
        stA(2 * t + 3);
        BARRIER();
        __builtin_amdgcn_s_setprio(1);
#pragma unroll
        for (int mm = 0; mm < 4; mm++)
#pragma unroll
            for (int nn = 0; nn < 4; nn++)
                acc[mm][nn] = __builtin_amdgcn_mfma_f32_16x16x32_bf16(a[mm], b[nn], acc[mm][nn], 0, 0, 0);
        __builtin_amdgcn_s_setprio(0);
        BARRIER();

        // ---- P1: ks=0, m 4-7 (B frags reused) ----
#pragma unroll
        for (int mm = 0; mm < 4; mm++) a2[mm] = ldA(s0, 4 + mm);
        stB(2 * t + 3);
        BARRIER();
        __builtin_amdgcn_s_setprio(1);
#pragma unroll
        for (int mm = 0; mm < 4; mm++)
#pragma unroll
            for (int nn = 0; nn < 4; nn++)
                acc[4 + mm][nn] = __builtin_amdgcn_mfma_f32_16x16x32_bf16(a2[mm], b[nn], acc[4 + mm][nn], 0, 0, 0);
        __builtin_amdgcn_s_setprio(0);
        BARRIER();

        // ---- P2: ks=1, m 0-3 ----
#pragma unroll
        for (int mm = 0; mm < 4; mm++) a[mm] = ldA(s1, mm);
#pragma unroll
        for (int nn = 0; nn < 4; nn++) b[nn] = ldB(s1, nn);
        stA(2 * t + 4);
        BARRIER();
        __builtin_amdgcn_s_setprio(1);
#pragma unroll
        for (int mm = 0; mm < 4; mm++)
#pragma unroll
            for (int nn = 0; nn < 4; nn++)
                acc[mm][nn] = __builtin_amdgcn_mfma_f32_16x16x32_bf16(a[mm], b[nn], acc[mm][nn], 0, 0, 0);
        __builtin_amdgcn_s_setprio(0);
        BARRIER();

        // ---- P3: ks=1, m 4-7; per-tile counted gate ----
#pragma unroll
        for (int mm = 0; mm < 4; mm++) a2[mm] = ldA(s1, 4 + mm);
        stB(2 * t + 4);
        asm volatile("s_waitcnt vmcnt(4)" ::: "memory");
        BARRIER();
        __builtin_amdgcn_s_setprio(1);
#pragma unroll
        for (int mm = 0; mm < 4; mm++)
#pragma unroll
            for (int nn = 0; nn < 4; nn++)
                acc[4 + mm][nn] = __builtin_amdgcn_mfma_f32_16x16x32_bf16(a2[mm], b[nn], acc[4 + mm][nn], 0, 0, 0);
        __builtin_amdgcn_s_setprio(0);
        BARRIER();
    }
    asm volatile("s_waitcnt vmcnt(0)" ::: "memory");

#pragma unroll
    for (int mm = 0; mm < 8; mm++) {
        int row = m0 + wr * 128 + mm * 16 + lhi * 4;
#pragma unroll
        for (int nn = 0; nn < 4; nn++) {
            int col = n0 + wc * 64 + nn * 16 + l15;
#pragma unroll
            for (int j = 0; j < 4; j++) {
                float vv = acc[mm][nn][j];
                size_t idx = (size_t)(row + j) * N + col;
                if (EPI == 0) {
                    Cb[idx] = __float2bfloat16(vv);
                } else if (EPI == 2) {
                    float o = vv + bias[col];
                    float u = 0.7978845608028654f * (o + 0.044715f * o * o * o);
                    Cb[idx] = __float2bfloat16(0.5f * o * (1.0f + tanhf(u)));
                } else {
                    atomicAdd(&Cf[idx], vv);
                }
            }
        }
    }
}

// ---------------- flash-style causal attention ----------------
// 1D grid of NH * (Sq/64) blocks, work-descending: heaviest q-tiles first.
__global__ __launch_bounds__(256) void attn_kernel(
    const bf16* __restrict__ qkv, bf16* __restrict__ o)
{
    __shared__ __align__(16) bf16 KsF[64 * 128];   // swizzled: slot s of row r holds block s^(r&7)
    __shared__ __align__(16) bf16 VtF[128 * 72];   // V^T with kv-block XOR swizzle
    __shared__ __align__(16) bf16 Pl[4][16][72];
    int rank = blockIdx.x;
    int qb = (Sq / 64 - 1) - rank / NH;    // heaviest first
    int head = rank % NH;
    const bf16* q = qkv + head * DH;
    const bf16* k = qkv + HDim + head * DH;
    const bf16* v = qkv + 2 * HDim + head * DH;
    int tid = threadIdx.x, lane = tid & 63, w = tid >> 6;
    int l15 = lane & 15, lhi = lane >> 4;
    int qrow0 = qb * 64 + w * 16;

    bf16x8 aq[4];
    const bf16* qbase = q + (size_t)(qrow0 + l15) * QKVDim;
#pragma unroll
    for (int kk = 0; kk < 4; kk++)
        aq[kk] = *reinterpret_cast<const bf16x8*>(qbase + kk * 32 + lhi * 8);

    const f32x4 zero4 = {0.f, 0.f, 0.f, 0.f};
    f32x4 acc_o[8];
#pragma unroll
    for (int db = 0; db < 8; db++) acc_o[db] = zero4;
    float mrow[4], lrow[4];
#pragma unroll
    for (int r = 0; r < 4; r++) { mrow[r] = -1e30f; lrow[r] = 0.f; }

    for (int kb = 0; kb <= qb; kb++) {
        int kv0 = kb * 64;
        __syncthreads();
#pragma unroll
        for (int c = 0; c < 4; c++) {
            int row = w * 16 + c * 4 + lhi;
            int cb = l15 ^ (row & 7);
            gload_lds16(k + (size_t)(kv0 + row) * QKVDim + cb * 8,
                        (char*)KsF + w * 4096 + c * 1024);
        }
#pragma unroll
        for (int i = 0; i < 4; i++) {
            int kv = (tid >> 4) + i * 16;
            int d0 = (tid & 15) * 8;
            bf16x8 vv = *reinterpret_cast<const bf16x8*>(
                v + (size_t)(kv0 + kv) * QKVDim + d0);
            int vb = kv >> 3, kr = kv & 7;
            int xr = (d0 >> 3) & 7;
#pragma unroll
            for (int j = 0; j < 8; j++) {
                int d = d0 + j;
                VtF[d * 72 + ((vb ^ xr) << 3) + kr] = ((const bf16*)&vv)[j];
            }
        }
        __syncthreads();

        f32x4 sacc[4];
#pragma unroll
        for (int nb = 0; nb < 4; nb++) {
            sacc[nb] = zero4;
            int krow = nb * 16 + l15;
#pragma unroll
            for (int kk = 0; kk < 4; kk++) {
                const char* kp = (const char*)KsF + krow * 256 +
                                 ((kk * 64 + lhi * 16) ^ ((krow & 7) << 4));
                bf16x8 bk = *reinterpret_cast<const bf16x8*>(kp);
                sacc[nb] = __builtin_amdgcn_mfma_f32_16x16x32_bf16(aq[kk], bk, sacc[nb], 0, 0, 0);
            }
        }

        bool diag = (kb == qb);
        float sv[4][4];
        float pm[4];
#pragma unroll
        for (int r = 0; r < 4; r++) pm[r] = -1e30f;
#pragma unroll
        for (int nb = 0; nb < 4; nb++) {
            int kvc = kv0 + nb * 16 + l15;
#pragma unroll
            for (int r = 0; r < 4; r++) {
                int qr = qrow0 + lhi * 4 + r;
                float s = sacc[nb][r] * ATT_SCALE;
                if (diag && kvc > qr) s = -1e30f;
                sv[nb][r] = s;
                pm[r] = fmaxf(pm[r], s);
            }
        }
#pragma unroll
        for (int off = 1; off < 16; off <<= 1)
#pragma unroll
            for (int r = 0; r < 4; r++)
                pm[r] = fmaxf(pm[r], __shfl_xor(pm[r], off));

        float ls[4];
#pragma unroll
        for (int r = 0; r < 4; r++) {
            float mnew = fmaxf(mrow[r], pm[r]);
            float sc = __expf(mrow[r] - mnew);
            mrow[r] = mnew;
            lrow[r] *= sc;
#pragma unroll
            for (int db = 0; db < 8; db++) acc_o[db][r] *= sc;
            float lsr = 0.f;
#pragma unroll
            for (int nb = 0; nb < 4; nb++) {
                float p = __expf(sv[nb][r] - mnew);
                sv[nb][r] = p;
                lsr += p;
            }
            ls[r] = lsr;
        }
#pragma unroll
        for (int off = 1; off < 16; off <<= 1)
#pragma unroll
            for (int r = 0; r < 4; r++)
                ls[r] += __shfl_xor(ls[r], off);
#pragma unroll
        for (int r = 0; r < 4; r++) lrow[r] += ls[r];

#pragma unroll
        for (int nb = 0; nb < 4; nb++)
#pragma unroll
            for (int r = 0; r < 4; r++)
                Pl[w][lhi * 4 + r][nb * 16 + l15] = __float2bfloat16(sv[nb][r]);

#pragma unroll
        for (int ks = 0; ks < 2; ks++) {
            bf16x8 ap = *reinterpret_cast<const bf16x8*>(&Pl[w][l15][ks * 32 + lhi * 8]);
#pragma unroll
            for (int db = 0; db < 8; db++) {
                int dv = db * 16 + l15;
                int blk = (ks * 4 + lhi) ^ ((dv >> 3) & 7);
                bf16x8 bv = *reinterpret_cast<const bf16x8*>(&VtF[dv * 72 + blk * 8]);
                acc_o[db] = __builtin_amdgcn_mfma_f32_16x16x32_bf16(ap, bv, acc_o[db], 0, 0, 0);
            }
        }
    }

#pragma unroll
    for (int db = 0; db < 8; db++)
#pragma unroll
        for (int r = 0; r < 4; r++) {
            int qr = qrow0 + lhi * 4 + r;
            float val = acc_o[db][r] / lrow[r];
            o[(size_t)qr * HDim + head * DH + db * 16 + l15] = __float2bfloat16(val);
        }
}

// ---------------- host launch ----------------
extern "C" void kernel_launch(void* const* d_in, const int* in_sizes, int n_in,
                              void* d_out, int out_size, void* d_ws, size_t ws_size,
                              hipStream_t stream)
{
    const float* x     = (const float*)d_in[0];
    const float* ln_g  = (const float*)d_in[1];
    const float* ln_b  = (const float*)d_in[2];
    const float* attng = (const float*)d_in[3];
    const float* Wq    = (const float*)d_in[4];
    const float* Wk    = (const float*)d_in[5];
    const float* Wv    = (const float*)d_in[6];
    const float* Wo    = (const float*)d_in[7];
    const float* W1    = (const float*)d_in[8];
    const float* b1    = (const float*)d_in[9];
    const float* W2    = (const float*)d_in[10];
    const float* b2    = (const float*)d_in[11];
    float* out = (float*)d_out;
    char* ws = (char*)d_ws;

    bf16*  wbuf = (bf16*)(ws + 0);           // 38 MB: transposed weights
    float* xnf  = (float*)(ws + 39845888);   // 16 MB: LN out fp32 -> x2 after Wo accum
    bf16*  hbuf = (bf16*)(ws + 56623104);    //  8 MB: rmsnorm bf16 -> x2 bf16
    bf16*  qkv  = (bf16*)(ws + 65011712);    // 36 MB: fused q|k|v; later FFN hidden
    bf16*  ob_  = (bf16*)(ws + 102760448);   // 12 MB: attention out
    bf16*  gb_  = qkv;

    ln_rms_kernel<<<Sq, 256, 0, stream>>>(x, ln_g, ln_b, attng, xnf, hbuf);

    transpose_cvt_kernel<<<dim3(HDim / 32, Dm / 32), 256, 0, stream>>>(Wq, wbuf, Dm, HDim);
    transpose_cvt_kernel<<<dim3(HDim / 32, Dm / 32), 256, 0, stream>>>(Wk, wbuf + (size_t)HDim * Dm, Dm, HDim);
    transpose_cvt_kernel<<<dim3(HDim / 32, Dm / 32), 256, 0, stream>>>(Wv, wbuf + (size_t)2 * HDim * Dm, Dm, HDim);
    gemm256_kernel<0><<<dim3(QKVDim / 256, Sq / 256, 1), 512, 0, stream>>>(
        hbuf, wbuf, Sq, QKVDim, Dm, Dm, qkv, nullptr, nullptr);

    attn_kernel<<<dim3(NH * Sq / 64), 256, 0, stream>>>(qkv, ob_);

    transpose_cvt_kernel<<<dim3(Dm / 32, HDim / 32), 256, 0, stream>>>(Wo, wbuf, HDim, Dm);
    gemm256_kernel<4><<<dim3(Dm / 256, Sq / 256, 4), 512, 0, stream>>>(
        ob_, wbuf, Sq, Dm, HDim, HDim / 4, nullptr, xnf, nullptr);
    cvt_bf16_kernel<<<(Sq * Dm) / (256 * 8), 256, 0, stream>>>(xnf, hbuf, Sq * Dm);

    transpose_cvt_kernel<<<dim3(FF / 32, Dm / 32), 256, 0, stream>>>(W1, wbuf, Dm, FF);
    gemm256_kernel<2><<<dim3(FF / 256, Sq / 256, 1), 512, 0, stream>>>(
        hbuf, wbuf, Sq, FF, Dm, Dm, gb_, nullptr, b1);

    transpose_cvt_kernel<<<dim3(Dm / 32, FF / 32), 256, 0, stream>>>(W2, wbuf, FF, Dm);
    prefill_kernel<<<(Sq * Dm) / (256 * 4), 256, 0, stream>>>(xnf, b2, out, Dm);
    gemm256_kernel<4><<<dim3(Dm / 256, Sq / 256, 4), 512, 0, stream>>>(
        gb_, wbuf, Sq, Dm, FF, FF / 4, nullptr, out, nullptr);
}

// Round 8
// 474.882 us; speedup vs baseline: 1.3420x; 1.3420x over previous
//
#include <hip/hip_runtime.h>
#include <hip/hip_bf16.h>

#define Sq 2048
#define Dm 2048
#define HDim 3072
#define QKVDim 9216
#define NH 24
#define DH 128
#define FF 8192
#define ATT_SCALE 0.08838834764831845f

using bf16 = __hip_bfloat16;
typedef __attribute__((ext_vector_type(8))) short bf16x8;
typedef __attribute__((ext_vector_type(4))) float f32x4;
typedef unsigned int u32;
typedef unsigned long long u64;
typedef __attribute__((ext_vector_type(4))) u32 u32x4;

// async global->LDS, 16B per lane; LDS dest = wave-uniform base + lane*16
__device__ __forceinline__ void gload_lds16(const void* g, void* l) {
    __builtin_amdgcn_global_load_lds(
        (const __attribute__((address_space(1))) void*)g,
        (__attribute__((address_space(3))) void*)l, 16, 0, 0);
}

// ---------------- LayerNorm + RMSNorm fused ----------------
__global__ __launch_bounds__(256) void ln_rms_kernel(
    const float* __restrict__ x, const float* __restrict__ g, const float* __restrict__ b,
    const float* __restrict__ ag, float* __restrict__ xnf, bf16* __restrict__ h)
{
    __shared__ float redA[4], redB[4], redC[4];
    int row = blockIdx.x;
    int t = threadIdx.x;
    int lane = t & 63, wid = t >> 6;
    const float* xr = x + (size_t)row * Dm;

    float v[8];
    float sum = 0.f, ssq = 0.f;
#pragma unroll
    for (int i = 0; i < 8; i++) {
        float f = xr[t + 256 * i];
        v[i] = f; sum += f; ssq += f * f;
    }
#pragma unroll
    for (int off = 32; off > 0; off >>= 1) {
        sum += __shfl_down(sum, off);
        ssq += __shfl_down(ssq, off);
    }
    if (lane == 0) { redA[wid] = sum; redB[wid] = ssq; }
    __syncthreads();
    sum = redA[0] + redA[1] + redA[2] + redA[3];
    ssq = redB[0] + redB[1] + redB[2] + redB[3];
    float mu = sum * (1.f / Dm);
    float var = ssq * (1.f / Dm) - mu * mu;
    float rstd = rsqrtf(var + 1e-5f);

    float xn[8];
    float s2 = 0.f;
#pragma unroll
    for (int i = 0; i < 8; i++) {
        int col = t + 256 * i;
        float xv = (v[i] - mu) * rstd * g[col] + b[col];
        xn[i] = xv;
        xnf[(size_t)row * Dm + col] = xv;
        s2 += xv * xv;
    }
#pragma unroll
    for (int off = 32; off > 0; off >>= 1) s2 += __shfl_down(s2, off);
    if (lane == 0) redC[wid] = s2;
    __syncthreads();
    s2 = redC[0] + redC[1] + redC[2] + redC[3];
    float rms = rsqrtf(s2 * (1.f / Dm) + 1e-5f);
#pragma unroll
    for (int i = 0; i < 8; i++) {
        int col = t + 256 * i;
        h[(size_t)row * Dm + col] = __float2bfloat16(xn[i] * rms * ag[col]);
    }
}

// ---------------- transpose + fp32->bf16 convert: W[K][N] -> Wt[N][K] ----------------
// vectorized: float4 loads, 8B bf16 stores
__global__ __launch_bounds__(256) void transpose_cvt_kernel(
    const float* __restrict__ W, bf16* __restrict__ Wt, int K, int N)
{
    __shared__ float tile[32][36];
    int n0 = blockIdx.x * 32, k0 = blockIdx.y * 32;
    int t = threadIdx.x;
    int r = t >> 3, c4 = (t & 7) * 4;
    f32x4 v = *reinterpret_cast<const f32x4*>(W + (size_t)(k0 + r) * N + n0 + c4);
    *reinterpret_cast<f32x4*>(&tile[r][c4]) = v;
    __syncthreads();
    int nr = t >> 3, kc = (t & 7) * 4;
    bf16 o4[4];
    o4[0] = __float2bfloat16(tile[kc + 0][nr]);
    o4[1] = __float2bfloat16(tile[kc + 1][nr]);
    o4[2] = __float2bfloat16(tile[kc + 2][nr]);
    o4[3] = __float2bfloat16(tile[kc + 3][nr]);
    *reinterpret_cast<u64*>(Wt + (size_t)(n0 + nr) * K + k0 + kc) = *reinterpret_cast<const u64*>(o4);
}

// ---------------- fp32 -> bf16 convert ----------------
__global__ __launch_bounds__(256) void cvt_bf16_kernel(
    const float* __restrict__ in, bf16* __restrict__ o, int n)
{
    int i = (blockIdx.x * 256 + threadIdx.x) * 8;
    if (i >= n) return;
    f32x4 a = *reinterpret_cast<const f32x4*>(in + i);
    f32x4 b = *reinterpret_cast<const f32x4*>(in + i + 4);
    bf16 r[8];
#pragma unroll
    for (int j = 0; j < 4; j++) { r[j] = __float2bfloat16(a[j]); r[4 + j] = __float2bfloat16(b[j]); }
    *reinterpret_cast<u32x4*>(o + i) = *reinterpret_cast<const u32x4*>(r);
}

// ---------------- prefill: out[row][col] = resid[row][col] + bias[col] ----------------
__global__ __launch_bounds__(256) void prefill_kernel(
    const float* __restrict__ resid, const float* __restrict__ bias,
    float* __restrict__ o, int N)
{
    int i = (blockIdx.x * 256 + threadIdx.x) * 4;
    int col = i % N;
    f32x4 r = *reinterpret_cast<const f32x4*>(resid + i);
    f32x4 b = *reinterpret_cast<const f32x4*>(bias + col);
    f32x4 ov = {r[0] + b[0], r[1] + b[1], r[2] + b[2], r[3] + b[3]};
    *reinterpret_cast<f32x4*>(o + i) = ov;
}

// ---------------- 128x128 bf16 MFMA GEMM (m97 structure, BK=64, swizzled) ------
// C[M][N] = A[M][K] * Bt[N][K]^T. 256 threads = 4 waves (2x2), 64x64 per wave.
// LDS: As/Bs [128 rows][64 K] linear, 16KB each (32KB total).
// Staging: global_load_lds 16B/lane; chunk c = 8 rows x 128B = 1024B; wave
// covers 32 rows = 4096B.  Both-sides XOR swizzle: stored 16B-block d of row
// r holds logical block d ^ (r&7) (source col pre-swizzled, reads XOR back).
// EPI 0: Cb = bf16(acc);  EPI 2: Cb = bf16(gelu(acc+bias));  EPI 4: atomicAdd(Cf, acc)
template <int EPI>
__global__ __launch_bounds__(256, 4) void gemm_kernel(
    const bf16* __restrict__ A, const bf16* __restrict__ Bt,
    int M, int N, int K, int Ksplit,
    bf16* Cb, float* Cf, const float* __restrict__ bias)
{
    __shared__ __align__(16) bf16 As[128 * 64];
    __shared__ __align__(16) bf16 Bs[128 * 64];
    int m0 = blockIdx.y * 128, n0 = blockIdx.x * 128;
    int kbeg = blockIdx.z * Ksplit, kend = kbeg + Ksplit;
    int tid = threadIdx.x;
    int lane = tid & 63, w = tid >> 6;
    int wr = w >> 1, wc = w & 1;
    int l15 = lane & 15, lhi = lane >> 4;

    // staging: chunk c covers rows w*32+c*8 .. +7 (128B each); lane L -> row +L>>3,
    // dest 16B-block L&7; pre-swizzled source block (L&7)^(L>>3)
    int srow = lane >> 3;
    int scol = ((lane & 7) ^ (lane >> 3)) * 8;

    const f32x4 zero4 = {0.f, 0.f, 0.f, 0.f};
    f32x4 acc[4][4];
#pragma unroll
    for (int m = 0; m < 4; m++)
#pragma unroll
        for (int n = 0; n < 4; n++) acc[m][n] = zero4;

    for (int k0 = kbeg; k0 < kend; k0 += 64) {
        __syncthreads();
#pragma unroll
        for (int c = 0; c < 4; c++) {
            int row = w * 32 + c * 8 + srow;
            gload_lds16(A + (size_t)(m0 + row) * K + k0 + scol,
                        (char*)As + w * 4096 + c * 1024);
            gload_lds16(Bt + (size_t)(n0 + row) * K + k0 + scol,
                        (char*)Bs + w * 4096 + c * 1024);
        }
        __syncthreads();   // full drain: staged data visible
#pragma unroll
        for (int ks = 0; ks < 2; ks++) {
            bf16x8 af[4], bfr[4];
#pragma unroll
            for (int m = 0; m < 4; m++) {
                int r = wr * 64 + m * 16 + l15;
                af[m] = *reinterpret_cast<const bf16x8*>(
                    &As[r * 64 + (((ks << 2) + lhi) ^ (r & 7)) * 8]);
            }
#pragma unroll
            for (int n = 0; n < 4; n++) {
                int r = wc * 64 + n * 16 + l15;
                bfr[n] = *reinterpret_cast<const bf16x8*>(
                    &Bs[r * 64 + (((ks << 2) + lhi) ^ (r & 7)) * 8]);
            }
#pragma unroll
            for (int m = 0; m < 4; m++)
#pragma unroll
                for (int n = 0; n < 4; n++)
                    acc[m][n] = __builtin_amdgcn_mfma_f32_16x16x32_bf16(af[m], bfr[n], acc[m][n], 0, 0, 0);
        }
    }

#pragma unroll
    for (int m = 0; m < 4; m++) {
        int row = m0 + wr * 64 + m * 16 + lhi * 4;
#pragma unroll
        for (int n = 0; n < 4; n++) {
            int col = n0 + wc * 64 + n * 16 + l15;
#pragma unroll
            for (int j = 0; j < 4; j++) {
                float vv = acc[m][n][j];
                size_t idx = (size_t)(row + j) * N + col;
                if (EPI == 0) {
                    Cb[idx] = __float2bfloat16(vv);
                } else if (EPI == 2) {
                    float o = vv + bias[col];
                    float u = 0.7978845608028654f * (o + 0.044715f * o * o * o);
                    Cb[idx] = __float2bfloat16(0.5f * o * (1.0f + tanhf(u)));
                } else {
                    atomicAdd(&Cf[idx], vv);
                }
            }
        }
    }
}

// ---------------- flash-style causal attention, double-buffered K/V -----------
// 1D grid NH*(Sq/64), work-descending. Per kb: K(kb+1) gload_lds + V(kb+1)->regs
// issued BEFORE compute of kb (latency hidden under QK/softmax/PV); V ds_write
// + single vmcnt(0) after the compute barrier.
__global__ __launch_bounds__(256) void attn_kernel(
    const bf16* __restrict__ qkv, bf16* __restrict__ o)
{
    __shared__ __align__(16) bf16 KsF[2][64 * 128];   // swizzled: slot s of row r = block s^(r&7)
    __shared__ __align__(16) bf16 VtF[2][128 * 72];   // V^T with kv-block XOR swizzle
    __shared__ __align__(16) bf16 Pl[4][16][72];
    int rank = blockIdx.x;
    int qb = (Sq / 64 - 1) - rank / NH;    // heaviest first
    int head = rank % NH;
    const bf16* q = qkv + head * DH;
    const bf16* k = qkv + HDim + head * DH;
    const bf16* v = qkv + 2 * HDim + head * DH;
    int tid = threadIdx.x, lane = tid & 63, w = tid >> 6;
    int l15 = lane & 15, lhi = lane >> 4;
    int qrow0 = qb * 64 + w * 16;

    bf16x8 aq[4];
    const bf16* qbase = q + (size_t)(qrow0 + l15) * QKVDim;
#pragma unroll
    for (int kk = 0; kk < 4; kk++)
        aq[kk] = *reinterpret_cast<const bf16x8*>(qbase + kk * 32 + lhi * 8);

    // stage helpers
    int krow_st = w * 16;                  // + c*4 + lhi
    int vkv = tid >> 4;                    // + i*16
    int vd0 = (tid & 15) * 8;

    const f32x4 zero4 = {0.f, 0.f, 0.f, 0.f};
    f32x4 acc_o[8];
#pragma unroll
    for (int db = 0; db < 8; db++) acc_o[db] = zero4;
    float mrow[4], lrow[4];
#pragma unroll
    for (int r = 0; r < 4; r++) { mrow[r] = -1e30f; lrow[r] = 0.f; }

    // prologue: stage kb=0 into buf 0
    {
#pragma unroll
        for (int c = 0; c < 4; c++) {
            int row = krow_st + c * 4 + lhi;
            int cb = l15 ^ (row & 7);
            gload_lds16(k + (size_t)row * QKVDim + cb * 8,
                        (char*)&KsF[0][0] + w * 4096 + c * 1024);
        }
#pragma unroll
        for (int i = 0; i < 4; i++) {
            int kv = vkv + i * 16;
            bf16x8 vv = *reinterpret_cast<const bf16x8*>(v + (size_t)kv * QKVDim + vd0);
            int vb = kv >> 3, kr = kv & 7, xr = (vd0 >> 3) & 7;
#pragma unroll
            for (int j = 0; j < 8; j++)
                VtF[0][(vd0 + j) * 72 + ((vb ^ xr) << 3) + kr] = ((const bf16*)&vv)[j];
        }
        asm volatile("s_waitcnt vmcnt(0)" ::: "memory");
        __syncthreads();
    }

    for (int kb = 0; kb <= qb; kb++) {
        int kv0 = kb * 64;
        int p = kb & 1;
        bf16x8 vreg[4];
        bool pref = (kb < qb);
        if (pref) {
            int nv0 = kv0 + 64;
#pragma unroll
            for (int c = 0; c < 4; c++) {
                int row = krow_st + c * 4 + lhi;
                int cb = l15 ^ (row & 7);
                gload_lds16(k + (size_t)(nv0 + row) * QKVDim + cb * 8,
                            (char*)&KsF[p ^ 1][0] + w * 4096 + c * 1024);
            }
#pragma unroll
            for (int i = 0; i < 4; i++) {
                int kv = vkv + i * 16;
                vreg[i] = *reinterpret_cast<const bf16x8*>(v + (size_t)(nv0 + kv) * QKVDim + vd0);
            }
        }

        // ---- compute on buf p ----
        f32x4 sacc[4];
#pragma unroll
        for (int nb = 0; nb < 4; nb++) {
            sacc[nb] = zero4;
            int krow = nb * 16 + l15;
#pragma unroll
            for (int kk = 0; kk < 4; kk++) {
                const char* kp = (const char*)&KsF[p][0] + krow * 256 +
                                 ((kk * 64 + lhi * 16) ^ ((krow & 7) << 4));
                bf16x8 bk = *reinterpret_cast<const bf16x8*>(kp);
                sacc[nb] = __builtin_amdgcn_mfma_f32_16x16x32_bf16(aq[kk], bk, sacc[nb], 0, 0, 0);
            }
        }

        bool diag = (kb == qb);
        float sv[4][4];
        float pm[4];
#pragma unroll
        for (int r = 0; r < 4; r++) pm[r] = -1e30f;
#pragma unroll
        for (int nb = 0; nb < 4; nb++) {
            int kvc = kv0 + nb * 16 + l15;
#pragma unroll
            for (int r = 0; r < 4; r++) {
                int qr = qrow0 + lhi * 4 + r;
                float s = sacc[nb][r] * ATT_SCALE;
                if (diag && kvc > qr) s = -1e30f;
                sv[nb][r] = s;
                pm[r] = fmaxf(pm[r], s);
            }
        }
#pragma unroll
        for (int off = 1; off < 16; off <<= 1)
#pragma unroll
            for (int r = 0; r < 4; r++)
                pm[r] = fmaxf(pm[r], __shfl_xor(pm[r], off));

        float ls[4];
#pragma unroll
        for (int r = 0; r < 4; r++) {
            float mnew = fmaxf(mrow[r], pm[r]);
            float sc = __expf(mrow[r] - mnew);
            mrow[r] = mnew;
            lrow[r] *= sc;
#pragma unroll
            for (int db = 0; db < 8; db++) acc_o[db][r] *= sc;
            float lsr = 0.f;
#pragma unroll
            for (int nb = 0; nb < 4; nb++) {
                float pp = __expf(sv[nb][r] - mnew);
                sv[nb][r] = pp;
                lsr += pp;
            }
            ls[r] = lsr;
        }
#pragma unroll
        for (int off = 1; off < 16; off <<= 1)
#pragma unroll
            for (int r = 0; r < 4; r++)
                ls[r] += __shfl_xor(ls[r], off);
#pragma unroll
        for (int r = 0; r < 4; r++) lrow[r] += ls[r];

#pragma unroll
        for (int nb = 0; nb < 4; nb++)
#pragma unroll
            for (int r = 0; r < 4; r++)
                Pl[w][lhi * 4 + r][nb * 16 + l15] = __float2bfloat16(sv[nb][r]);

#pragma unroll
        for (int ks = 0; ks < 2; ks++) {
            bf16x8 ap = *reinterpret_cast<const bf16x8*>(&Pl[w][l15][ks * 32 + lhi * 8]);
#pragma unroll
            for (int db = 0; db < 8; db++) {
                int dv = db * 16 + l15;
                int blk = (ks * 4 + lhi) ^ ((dv >> 3) & 7);
                bf16x8 bv = *reinterpret_cast<const bf16x8*>(&VtF[p][dv * 72 + blk * 8]);
                acc_o[db] = __builtin_amdgcn_mfma_f32_16x16x32_bf16(ap, bv, acc_o[db], 0, 0, 0);
            }
        }

        __syncthreads();                      // everyone done reading buf p
        if (pref) {
#pragma unroll
            for (int i = 0; i < 4; i++) {
                int kv = vkv + i * 16;
                int vb = kv >> 3, kr = kv & 7, xr = (vd0 >> 3) & 7;
#pragma unroll
                for (int j = 0; j < 8; j++)
                    VtF[p ^ 1][(vd0 + j) * 72 + ((vb ^ xr) << 3) + kr] = ((const bf16*)&vreg[i])[j];
            }
            asm volatile("s_waitcnt vmcnt(0)" ::: "memory");
            __syncthreads();                  // buf p^1 (K via DMA, V via ds_write) ready
        }
    }

#pragma unroll
    for (int db = 0; db < 8; db++)
#pragma unroll
        for (int r = 0; r < 4; r++) {
            int qr = qrow0 + lhi * 4 + r;
            float val = acc_o[db][r] / lrow[r];
            o[(size_t)qr * HDim + head * DH + db * 16 + l15] = __float2bfloat16(val);
        }
}

// ---------------- host launch ----------------
extern "C" void kernel_launch(void* const* d_in, const int* in_sizes, int n_in,
                              void* d_out, int out_size, void* d_ws, size_t ws_size,
                              hipStream_t stream)
{
    const float* x     = (const float*)d_in[0];
    const float* ln_g  = (const float*)d_in[1];
    const float* ln_b  = (const float*)d_in[2];
    const float* attng = (const float*)d_in[3];
    const float* Wq    = (const float*)d_in[4];
    const float* Wk    = (const float*)d_in[5];
    const float* Wv    = (const float*)d_in[6];
    const float* Wo    = (const float*)d_in[7];
    const float* W1    = (const float*)d_in[8];
    const float* b1    = (const float*)d_in[9];
    const float* W2    = (const float*)d_in[10];
    const float* b2    = (const float*)d_in[11];
    float* out = (float*)d_out;
    char* ws = (char*)d_ws;

    bf16*  wbuf = (bf16*)(ws + 0);           // 38 MB: transposed weights
    float* xnf  = (float*)(ws + 39845888);   // 16 MB: LN out fp32 -> x2 after Wo accum
    bf16*  hbuf = (bf16*)(ws + 56623104);    //  8 MB: rmsnorm bf16 -> x2 bf16
    bf16*  qkv  = (bf16*)(ws + 65011712);    // 36 MB: fused q|k|v; later FFN hidden
    bf16*  ob_  = (bf16*)(ws + 102760448);   // 12 MB: attention out
    bf16*  gb_  = qkv;

    ln_rms_kernel<<<Sq, 256, 0, stream>>>(x, ln_g, ln_b, attng, xnf, hbuf);

    transpose_cvt_kernel<<<dim3(HDim / 32, Dm / 32), 256, 0, stream>>>(Wq, wbuf, Dm, HDim);
    transpose_cvt_kernel<<<dim3(HDim / 32, Dm / 32), 256, 0, stream>>>(Wk, wbuf + (size_t)HDim * Dm, Dm, HDim);
    transpose_cvt_kernel<<<dim3(HDim / 32, Dm / 32), 256, 0, stream>>>(Wv, wbuf + (size_t)2 * HDim * Dm, Dm, HDim);
    gemm_kernel<0><<<dim3(QKVDim / 128, Sq / 128, 1), 256, 0, stream>>>(
        hbuf, wbuf, Sq, QKVDim, Dm, Dm, qkv, nullptr, nullptr);

    attn_kernel<<<dim3(NH * Sq / 64), 256, 0, stream>>>(qkv, ob_);

    transpose_cvt_kernel<<<dim3(Dm / 32, HDim / 32), 256, 0, stream>>>(Wo, wbuf, HDim, Dm);
    gemm_kernel<4><<<dim3(Dm / 128, Sq / 128, 2), 256, 0, stream>>>(
        ob_, wbuf, Sq, Dm, HDim, HDim / 2, nullptr, xnf, nullptr);
    cvt_bf16_kernel<<<(Sq * Dm) / (256 * 8), 256, 0, stream>>>(xnf, hbuf, Sq * Dm);

    transpose_cvt_kernel<<<dim3(FF / 32, Dm / 32), 256, 0, stream>>>(W1, wbuf, Dm, FF);
    gemm_kernel<2><<<dim3(FF / 128, Sq / 128, 1), 256, 0, stream>>>(
        hbuf, wbuf, Sq, FF, Dm, Dm, gb_, nullptr, b1);

    transpose_cvt_kernel<<<dim3(Dm / 32, FF / 32), 256, 0, stream>>>(W2, wbuf, FF, Dm);
    prefill_kernel<<<(Sq * Dm) / (256 * 4), 256, 0, stream>>>(xnf, b2, out, Dm);
    gemm_kernel<4><<<dim3(Dm / 128, Sq / 128, 2), 256, 0, stream>>>(
        gb_, wbuf, Sq, Dm, FF, FF / 2, nullptr, out, nullptr);
}